// Round 5
// baseline (152.089 us; speedup 1.0000x reference)
//
#include <hip/hip_runtime.h>
#include <hip/hip_bf16.h>

// B=2, M=2048, HID=1024, NH=16, D=64.  No softmax in the reference, so
//   out = ((h Wq^T)(h Wk^T)^T (h Wv^T)) Wo^T
// reassociates twice:  S_{b,h} = K_h^T V_h  (64x64), and
//   out_b = Q_b @ T_b   with  T_b[h*64+d, n] = sum_j S_{b,h}[d,j] Wo[n, h*64+j]
//
// Dtypes: inputs fp32, d_out fp32; internal bf16 with fp32 accumulate.
//
// Round-16: r15 verified the 128x384 / 128x128 counted-vmcnt template at
// 100% CU coverage (151.5us) but under-delivered vs prediction.  Cause: the
// phase serializes LDS and MFMA by construction -- ds_reads, then an
// explicit lgkmcnt(0)+sched_barrier(0), then MFMAs.  Per CU per phase the
// two sides are comparable (~80KB LDS ~ 640-940cyc vs 192 MFMA ~ 740cyc),
// so the forced serialization nearly doubles phase time.  The pre-MFMA
// drain is NOT needed for correctness: ds_reads here are plain C++ loads
// (not inline asm), so the compiler emits fine-grained per-MFMA lgkmcnt.
// r16 keeps the r14/r15 schedule and moves the lgkmcnt(0) AFTER the MFMA
// cluster (it only serves the WAR hazard: my reads must complete before I
// cross the phase-end barrier, since buf kt&3 is overwritten by stages
// issued in phase kt+1).  A sched_barrier(0) immediately after each
// phase-end s_barrier prevents the compiler from hoisting next-phase
// ds_reads between vmcnt and barrier (raw s_barrier is not a compiler
// fence -- that would re-import r12's cross-wave race).
// Lessons kept: no dense-reduction atomics (r6->r7); never trade
// high-occupancy FLOPs for low-occupancy FLOPs (r8); price redundant
// re-reads by XCD locality (r10); vmcnt waits are per-wave -- wait must
// precede a barrier (r12); count LDS bytes per phase (r13); grid must
// cover all 256 CUs (r14); don't serialize LDS and MFMA with explicit
// drains when dataflow suffices (r15).
//
// Pipeline:
//   0. prep: h->hb (bf16), Wq|Wk|Wv->wcat (bf16)
//   1. QKVb = hb @ wcat^T        (4096x3072 bf16)            [gemm32<384>]
//   2. Spart[bh,c] = K^T V partial over 128 rows             [VALU]
//   2b. S = sum_c Spart          (each line read once)       [BW]
//   3. Tt[b][n,k] = (S_h Wo_h^T)^T  (2 x 1024x1024 bf16)     [VALU]
//   4. out = Q @ Tt_b^T          (4096x1024 fp32 -> d_out)   [gemm32<128>]

typedef unsigned short u16;
typedef unsigned int u32;
typedef __attribute__((ext_vector_type(8))) short bf16x8;
typedef __attribute__((ext_vector_type(4))) float f32x4;

__device__ __forceinline__ void async_copy16(void* lds, const void* g) {
  __builtin_amdgcn_global_load_lds((const __attribute__((address_space(1))) void*)g,
                                   (__attribute__((address_space(3))) void*)lds,
                                   16, 0, 0);
}

__device__ __forceinline__ u16 f2bf(float f) {
  union { __hip_bfloat16 h; u16 u; } c;
  c.h = __float2bfloat16(f);
  return c.u;
}
__device__ __forceinline__ float bflo(u32 w) {
  union { u32 u; float f; } c; c.u = w << 16; return c.f;
}
__device__ __forceinline__ float bfhi(u32 w) {
  union { u32 u; float f; } c; c.u = w & 0xFFFF0000u; return c.f;
}
__device__ __forceinline__ ushort4 cvt4(float4 v) {
  ushort4 o; o.x = f2bf(v.x); o.y = f2bf(v.y); o.z = f2bf(v.z); o.w = f2bf(v.w);
  return o;
}

template <int N> __device__ __forceinline__ void vw() {
  if constexpr (N == 8)      asm volatile("s_waitcnt vmcnt(8)" ::: "memory");
  else if constexpr (N == 4) asm volatile("s_waitcnt vmcnt(4)" ::: "memory");
  else if constexpr (N == 2) asm volatile("s_waitcnt vmcnt(2)" ::: "memory");
  else if constexpr (N == 0) asm volatile("s_waitcnt vmcnt(0)" ::: "memory");
}

// ---------------------------------------------------------------- prep ------
__global__ __launch_bounds__(256) void prep(const float4* __restrict__ h,
                                            const float4* __restrict__ wq,
                                            const float4* __restrict__ wk,
                                            const float4* __restrict__ wv,
                                            ushort4* __restrict__ hb,
                                            ushort4* __restrict__ wcat) {
  int i = blockIdx.x * 256 + threadIdx.x;  // float4 units
  if (i < 1048576) { hb[i] = cvt4(h[i]); return; }          // h: 4096x1024
  i -= 1048576;
  if (i < 262144) { wcat[i] = cvt4(wq[i]); return; }
  i -= 262144;
  if (i < 262144) { wcat[262144 + i] = cvt4(wk[i]); return; }
  i -= 262144;
  wcat[524288 + i] = cvt4(wv[i]);
}

// ------------------------------ BK=32 4-buffer counted-vmcnt NT GEMM --------
// C[m,n] = sum_k A[m*lda+k] * B[n*1024+k], M=4096, K=1024.  BM=128 fixed.
// grid 256 = 32 m-tiles x 8 n-tiles (XCD-swizzled), 512 thr = 8 waves (2x4).
// One phase per K-tile: {MI+NI ds_read_b128 | stage tile kt+3 | MI*NI MFMA
// interleaved by compiler dataflow (setprio) | lgkmcnt(0) | vmcnt(2V) |
// s_barrier | sched_barrier}.
// Safety: read buf kt&3 vs stage buf (kt+3)&3 always distinct; per-wave
// lgkmcnt(0) precedes the phase barrier (WAR-safe: buf kt&3 overwritten by
// stages issued in phase kt+1, after that barrier); tile kt+1 gated by all
// waves' vmcnt+barrier at end of phase kt; sched_barrier(0) after the
// barrier pins next-phase ds_reads behind it (r12 race, compiler edition).

#define NOPW ((void)0)

#define PHASE(KT, DO_STAGE, VWAIT)                                           \
  do {                                                                       \
    const u16* Ab = &Als[(KT) & 3][wm * 32 + aoff];                          \
    const u16* Bb = &Bls[(KT) & 3][wn * 32 + aoff];                          \
    bf16x8 af[MI], bv[NI];                                                   \
    _Pragma("unroll") for (int i = 0; i < MI; ++i)                           \
        af[i] = *(const bf16x8*)(Ab + i * 512);                              \
    _Pragma("unroll") for (int j = 0; j < NI; ++j)                           \
        bv[j] = *(const bf16x8*)(Bb + j * 512);                              \
    DO_STAGE;                                                                \
    __builtin_amdgcn_s_setprio(1);                                           \
    _Pragma("unroll") for (int i = 0; i < MI; ++i)                           \
        _Pragma("unroll") for (int j = 0; j < NI; ++j)                       \
            acc[i][j] = __builtin_amdgcn_mfma_f32_16x16x32_bf16(             \
                af[i], bv[j], acc[i][j], 0, 0, 0);                           \
    __builtin_amdgcn_s_setprio(0);                                           \
    asm volatile("s_waitcnt lgkmcnt(0)" ::: "memory");                       \
    VWAIT;                                                                   \
    __builtin_amdgcn_s_barrier();                                            \
    __builtin_amdgcn_sched_barrier(0);                                       \
  } while (0)

template <bool BF16_OUT, int BN>
__global__ __launch_bounds__(512, 2) void gemm32(const u16* __restrict__ A,
                                                 int lda,
                                                 const u16* __restrict__ B0,
                                                 const u16* __restrict__ B1,
                                                 void* __restrict__ Cv,
                                                 int N) {
  constexpr int SA = 1;              // A staging insts/thread (BM=128)
  constexpr int SB = BN / 128;       // B staging insts/thread
  constexpr int V  = SA + SB;        // insts/thread per tile
  constexpr int MI = 4;              // 64-row wave half -> 4 m-frags
  constexpr int NI = BN / 4 / 16;    // wave covers BN/4 cols

  __shared__ u16 Als[4][128 * 32];
  __shared__ u16 Bls[4][BN * 32];
  const int t = threadIdx.x;
  const int lane = t & 63;
  const int wave = t >> 6;                 // 0..7
  const int wm = (wave >> 2) * 64;         // 0 / 64
  const int wn = (wave & 3) * (BN / 4);    // mult of 16
  const int lrow = lane & 15;
  const int quad = lane >> 4;

  // bijective XCD swizzle (256 blocks): XCD x -> m-tiles {4x..4x+3} x all 8 n
  const int bid = blockIdx.x;
  const int xcd = bid & 7;
  const int c = bid >> 3;                  // 0..31
  const int m0 = (xcd * 4 + (c >> 3)) * 128;
  const int n0 = (c & 7) * BN;
  const u16* B = (B1 != nullptr && m0 >= 2048) ? B1 : B0;

  // staging: one inst = 16 rows x 32 k = 1 KB; lane l -> row +(l>>2),
  // LDS slot l&3 holding global k-granule (l&3)^((l>>3)&3)  (linear dest).
  const int srow = lane >> 2;                       // 0..15
  const int sgk  = (lane & 3) ^ ((lane >> 3) & 3);  // global k-granule
  const u16* Ag = A + (size_t)(m0 + wave * (SA * 16) + srow) * lda + sgk * 8;
  const u16* Bg = B + (size_t)(n0 + wave * (SB * 16) + srow) * 1024 + sgk * 8;

  // read swizzle: slot holding granule `quad` at row r is quad^((r>>1)&3);
  // all row bases are multiples of 16, so (r>>1)&3 == (lrow>>1)&3.
  const int swz = (lrow >> 1) & 3;
  const int aoff = lrow * 32 + ((quad ^ swz) << 3);  // u16 units

  f32x4 acc[MI][NI];
#pragma unroll
  for (int i = 0; i < MI; ++i)
#pragma unroll
    for (int j = 0; j < NI; ++j) acc[i][j] = {0.f, 0.f, 0.f, 0.f};

  // stage tile kt (V insts/thread: SA for A, SB for B) into buf kt&3
  auto stage = [&](int kt) {
    const int buf = kt & 3;
#pragma unroll
    for (int j = 0; j < SA; ++j) {
      const int ch = wave * SA + j;                  // 16-row chunk index
      async_copy16(&Als[buf][ch * 512 + lane * 8],
                   Ag + (size_t)(j * 16) * lda + kt * 32);
    }
#pragma unroll
    for (int j = 0; j < SB; ++j) {
      const int ch = wave * SB + j;
      async_copy16(&Bls[buf][ch * 512 + lane * 8],
                   Bg + (size_t)(j * 16) * 1024 + kt * 32);
    }
  };

  // prologue: stage tiles 0,1,2 (3V insts); wait tile0 (<=2V left); barrier.
  stage(0); stage(1); stage(2);
  vw<2 * V>();
  __builtin_amdgcn_s_barrier();
  __builtin_amdgcn_sched_barrier(0);

  // steady: phase kt stages kt+3 (3V in flight), vw<2V> drains tile kt+1.
#pragma unroll 1
  for (int kt = 0; kt < 29; ++kt) {
    PHASE(kt, stage(kt + 3), vw<2 * V>());
  }
  PHASE(29, NOPW, vw<V>());   // in flight: t30,t31 -> drain t30
  PHASE(30, NOPW, vw<0>());   // drain t31
  PHASE(31, NOPW, NOPW);

  // C/D layout (verified m89/m91): col = lane&15, row = (lane>>4)*4 + r
  const int crow0 = m0 + wm + quad * 4;
  const int ccol0 = n0 + wn + lrow;
#pragma unroll
  for (int mf = 0; mf < MI; ++mf)
#pragma unroll
    for (int nf = 0; nf < NI; ++nf)
#pragma unroll
      for (int r = 0; r < 4; ++r) {
        const size_t idx = (size_t)(crow0 + mf * 16 + r) * N + ccol0 + nf * 16;
        if (BF16_OUT) ((u16*)Cv)[idx]   = f2bf(acc[mf][nf][r]);
        else          ((float*)Cv)[idx] = acc[mf][nf][r];
      }
}

// --------------------------------------------- Spart = partial K^T V --------
__global__ __launch_bounds__(256) void s_kernel(const u16* __restrict__ QKV,
                                                float* __restrict__ Spart) {
  const int bh = blockIdx.x;
  const int b = bh >> 4, hh = bh & 15;
  const int row0 = b * 2048 + blockIdx.y * 128;
  const u16* Kg = QKV + (size_t)row0 * 3072 + 1024 + hh * 64;

  __shared__ float Ks[64][64];
  __shared__ float Vs[64][64];
  const int t = threadIdx.x;
  const int lr = t >> 2;        // 0..63 row within stage
  const int lc = (t & 3) * 16;  // col group (16 cols)
  const int d1 = (t >> 4) * 4;
  const int d2 = (t & 15) * 4;

  float acc[4][4] = {};

  for (int r0 = 0; r0 < 128; r0 += 64) {
    const u16* kp = Kg + (size_t)(r0 + lr) * 3072 + lc;
    const uint4 kw0 = *(const uint4*)kp;
    const uint4 kw1 = *(const uint4*)(kp + 8);
    const uint4 vw0 = *(const uint4*)(kp + 1024);  // V = K + 1024 cols
    const uint4 vw1 = *(const uint4*)(kp + 1032);
    __syncthreads();  // prev-iter readers done
    float* kd = &Ks[lr][lc];
    *(float4*)(kd)      = float4{bflo(kw0.x), bfhi(kw0.x), bflo(kw0.y), bfhi(kw0.y)};
    *(float4*)(kd + 4)  = float4{bflo(kw0.z), bfhi(kw0.z), bflo(kw0.w), bfhi(kw0.w)};
    *(float4*)(kd + 8)  = float4{bflo(kw1.x), bfhi(kw1.x), bflo(kw1.y), bfhi(kw1.y)};
    *(float4*)(kd + 12) = float4{bflo(kw1.z), bfhi(kw1.z), bflo(kw1.w), bfhi(kw1.w)};
    float* vd = &Vs[lr][lc];
    *(float4*)(vd)      = float4{bflo(vw0.x), bfhi(vw0.x), bflo(vw0.y), bfhi(vw0.y)};
    *(float4*)(vd + 4)  = float4{bflo(vw0.z), bfhi(vw0.z), bflo(vw0.w), bfhi(vw0.w)};
    *(float4*)(vd + 8)  = float4{bflo(vw1.x), bfhi(vw1.x), bflo(vw1.y), bfhi(vw1.y)};
    *(float4*)(vd + 12) = float4{bflo(vw1.z), bfhi(vw1.z), bflo(vw1.w), bfhi(vw1.w)};
    __syncthreads();
#pragma unroll
    for (int r = 0; r < 64; ++r) {
      float kv[4], vv[4];
      *(float4*)kv = *(const float4*)&Ks[r][d1];
      *(float4*)vv = *(const float4*)&Vs[r][d2];
#pragma unroll
      for (int i = 0; i < 4; ++i)
#pragma unroll
        for (int j = 0; j < 4; ++j) acc[i][j] += kv[i] * vv[j];
    }
  }
  float* Sp = Spart + ((size_t)bh * 16 + blockIdx.y) * 4096;
#pragma unroll
  for (int i = 0; i < 4; ++i)
    *(float4*)&Sp[(d1 + i) * 64 + d2] =
        float4{acc[i][0], acc[i][1], acc[i][2], acc[i][3]};
}

// ---------------------------------------------------- S = sum_c Spart -------
__global__ __launch_bounds__(256) void reduce_s(const float4* __restrict__ Spart,
                                                float4* __restrict__ S) {
  const int g = blockIdx.x * 256 + threadIdx.x;  // 0..32767
  const int bh = g >> 10, j = g & 1023;
  const float4* p = Spart + (size_t)bh * 16384 + j;  // 16 chunks * 1024 f4
  float4 a = {0.f, 0.f, 0.f, 0.f};
#pragma unroll
  for (int c = 0; c < 16; ++c) {
    const float4 v = p[(size_t)c * 1024];
    a.x += v.x; a.y += v.y; a.z += v.z; a.w += v.w;
  }
  S[g] = a;
}

// ------------------------------------------- Tt = (S_h Wo_h^T)^T ------------
__global__ __launch_bounds__(256) void t_kernel(const float* __restrict__ S,
                                                const float* __restrict__ Wo,
                                                u16* __restrict__ Tt) {
  const int n0 = blockIdx.x * 128;
  const int hh = blockIdx.y;
  const int b  = blockIdx.z;
  __shared__ float Ss[64][68];
  __shared__ float Ws[128][68];
  const int t = threadIdx.x;
  {
    const float* sg = S + (size_t)(b * 16 + hh) * 4096 + (t >> 2) * 64 + (t & 3) * 16;
    float* sd = &Ss[t >> 2][(t & 3) * 16];
#pragma unroll
    for (int i = 0; i < 4; ++i) *(float4*)(sd + 4 * i) = *(const float4*)(sg + 4 * i);
    const float* wg = Wo + (size_t)(n0 + (t >> 1)) * 1024 + hh * 64 + (t & 1) * 32;
    float* wd = &Ws[t >> 1][(t & 1) * 32];
#pragma unroll
    for (int i = 0; i < 8; ++i) *(float4*)(wd + 4 * i) = *(const float4*)(wg + 4 * i);
  }
  __syncthreads();

  const int td = (t >> 4) * 4;  // d = td..td+3
  const int tn = t & 15;        // n = n0 + tn + 16k
  float acc[4][8] = {};
  for (int jj = 0; jj < 64; jj += 4) {
    float4 sv[4], wv[8];
#pragma unroll
    for (int i = 0; i < 4; ++i) sv[i] = *(const float4*)&Ss[td + i][jj];
#pragma unroll
    for (int k = 0; k < 8; ++k) wv[k] = *(const float4*)&Ws[tn + 16 * k][jj];
#pragma unroll
    for (int i = 0; i < 4; ++i)
#pragma unroll
      for (int k = 0; k < 8; ++k)
        acc[i][k] += sv[i].x * wv[k].x + sv[i].y * wv[k].y +
                     sv[i].z * wv[k].z + sv[i].w * wv[k].w;
  }

  u16* tp = Tt + (size_t)b * 1048576;
#pragma unroll
  for (int k = 0; k < 8; ++k) {
    const int n = n0 + tn + 16 * k;
    ushort4 o;
    o.x = f2bf(acc[0][k]); o.y = f2bf(acc[1][k]);
    o.z = f2bf(acc[2][k]); o.w = f2bf(acc[3][k]);
    *(ushort4*)&tp[(size_t)n * 1024 + hh * 64 + td] = o;
  }
}

// ---------------------------------------------------------------------------
extern "C" void kernel_launch(void* const* d_in, const int* in_sizes, int n_in,
                              void* d_out, int out_size, void* d_ws, size_t ws_size,
                              hipStream_t stream) {
  const float* h  = (const float*)d_in[0];  // (4096, 1024) fp32
  // d_in[1] = key_pe: dead branch in reference, unused.
  const float* Wq = (const float*)d_in[2];
  const float* Wk = (const float*)d_in[3];
  const float* Wv = (const float*)d_in[4];
  const float* Wo = (const float*)d_in[5];

  char* ws = (char*)d_ws;
  u16*   hb    = (u16*)(ws);                    // 4096*1024*2 = 8 MiB @ 0
  u16*   wcat  = (u16*)(ws + (8ull  << 20));    // 3072*1024*2 = 6 MiB
  u16*   QKVb  = (u16*)(ws + (16ull << 20));    // 4096*3072*2 = 24 MiB
  float* S     = (float*)(ws + (40ull << 20));  // 32*64*64*4  = 0.5 MiB
  u16*   Tt    = (u16*)(ws + (41ull << 20));    // 2*1024*1024*2 = 4 MiB
  float* Spart = (float*)(ws + (48ull << 20));  // 512*64*64*4 = 8 MiB
  // total ws use: 56 MiB (ws_size = 256 MiB)

  prep<<<7168, 256, 0, stream>>>((const float4*)h, (const float4*)Wq,
                                 (const float4*)Wk, (const float4*)Wv,
                                 (ushort4*)hb, (ushort4*)wcat);
  // QKVb = hb @ wcat^T : (4096 x 3072), K=1024, 256 blocks = 1/CU, 8 waves
  gemm32<true, 384><<<256, 512, 0, stream>>>(hb, 1024, wcat, nullptr,
                                             QKVb, 3072);
  s_kernel<<<dim3(32, 16), 256, 0, stream>>>(QKVb, Spart);
  reduce_s<<<128, 256, 0, stream>>>((const float4*)Spart, (float4*)S);
  t_kernel<<<dim3(8, 16, 2), 256, 0, stream>>>(S, Wo, Tt);
  // out = Q @ Tt_b^T : (4096 x 1024), K=1024, 256 blocks = 1/CU, 8 waves
  gemm32<false, 128><<<256, 512, 0, stream>>>(QKVb, 3072, Tt, Tt + 1048576,
                                              d_out, 1024);
}